// Round 1
// baseline (444.093 us; speedup 1.0000x reference)
//
#include <hip/hip_runtime.h>
#include <cstdint>
#include <cstddef>

#define N_ANCH 25200
#define NB0 19200
#define NB1 24000
#define TOPK_N 4096
#define CONF_T 0.001
#define NMS_T 0.6
#define IMGS 640.0
#define CS 1575   // N_ANCH / 16 exactly

typedef unsigned long long u64;

struct WS {
  double sc[N_ANCH];          // masked score (sc or -1.0)
  double box[N_ANCH][4];      // clipped normalized boxes, fp64
  int    cls[N_ANCH];
  int    rank[N_ANCH];
  double tbox[TOPK_N][4];
  double tarea[TOPK_N];
  double tsc[TOPK_N];
  int    tcls[TOPK_N];
  u64    supT[TOPK_N * 64];   // supT[i*64+w] bit b: j=w*64+b suppresses i
};

__device__ __forceinline__ double dsigmoid(double x) { return 1.0 / (1.0 + exp(-x)); }

__global__ void k_decode(const float* __restrict__ ps, const float* __restrict__ pm,
                         const float* __restrict__ pl, const float* __restrict__ anch,
                         WS* __restrict__ ws) {
  int a = blockIdx.x * 256 + threadIdx.x;
  if (a >= N_ANCH) return;
  const float* p; int W, base, lvl; double stride;
  if (a < NB0)      { p = ps; W = 80; base = 0;   lvl = 0; stride = 8.0; }
  else if (a < NB1) { p = pm; W = 40; base = NB0; lvl = 1; stride = 16.0; }
  else              { p = pl; W = 20; base = NB1; lvl = 2; stride = 32.0; }
  int e = a - base;
  int pos = e / 3;
  int k = e - 3 * pos;
  int HW = W * W;
  int x = pos % W, y = pos / W;

  // objectness
  double sobj = dsigmoid((double)p[(size_t)k * HW + pos]);

  // class softmax max + argmax (two-pass, fp64)
  const float* pc = p + (size_t)(3 + k * 80) * HW + pos;
  double m = -1e300; int am = 0;
  for (int c = 0; c < 80; ++c) {
    double v = (double)pc[(size_t)c * HW];
    if (v > m) { m = v; am = c; }
  }
  double ssum = 0.0;
  for (int c = 0; c < 80; ++c) {
    double v = (double)pc[(size_t)c * HW];
    ssum += exp(v - m);
  }
  double sc = sobj * (1.0 / ssum);

  // box decode
  const float* pr = p + (size_t)(243 + k * 4) * HW + pos;
  double tx = (double)pr[0];
  double ty = (double)pr[(size_t)HW];
  double tw = (double)pr[(size_t)2 * HW];
  double th = (double)pr[(size_t)3 * HW];
  double cx = (dsigmoid(tx) + (double)x) * stride;
  double cy = (dsigmoid(ty) + (double)y) * stride;
  double aw = (double)anch[lvl * 6 + k * 2 + 0];
  double ah = (double)anch[lvl * 6 + k * 2 + 1];
  double bw = exp(tw) * aw;
  double bh = exp(th) * ah;
  double x1 = fmin(fmax((cx - 0.5 * bw) / IMGS, 0.0), 1.0);
  double y1 = fmin(fmax((cy - 0.5 * bh) / IMGS, 0.0), 1.0);
  double x2 = fmin(fmax((cx + 0.5 * bw) / IMGS, 0.0), 1.0);
  double y2 = fmin(fmax((cy + 0.5 * bh) / IMGS, 0.0), 1.0);

  ws->box[a][0] = x1; ws->box[a][1] = y1;
  ws->box[a][2] = x2; ws->box[a][3] = y2;
  ws->cls[a] = am;
  ws->sc[a] = (sc >= CONF_T) ? sc : -1.0;
  ws->rank[a] = 0;
}

// rank[i] = #{ j : sc_j > sc_i  or (sc_j == sc_i and j < i) }
__global__ void k_count(WS* __restrict__ ws) {
  __shared__ double s[CS];
  int j0 = blockIdx.y * CS;
  for (int t = threadIdx.x; t < CS; t += 256) s[t] = ws->sc[j0 + t];
  __syncthreads();
  int i = blockIdx.x * 256 + threadIdx.x;
  if (i >= N_ANCH) return;
  double si = ws->sc[i];
  int cnt = 0;
  for (int t = 0; t < CS; ++t) {
    double sj = s[t];
    cnt += (int)((sj > si) | ((sj == si) & ((j0 + t) < i)));
  }
  atomicAdd(&ws->rank[i], cnt);
}

__global__ void k_scatter(WS* __restrict__ ws, float* __restrict__ out) {
  int i = blockIdx.x * 256 + threadIdx.x;
  if (i >= N_ANCH) return;
  int r = ws->rank[i];
  if (r >= TOPK_N) return;
  double b0 = ws->box[i][0], b1 = ws->box[i][1];
  double b2 = ws->box[i][2], b3 = ws->box[i][3];
  double s  = ws->sc[i];
  int    c  = ws->cls[i];
  ws->tbox[r][0] = b0; ws->tbox[r][1] = b1;
  ws->tbox[r][2] = b2; ws->tbox[r][3] = b3;
  ws->tarea[r] = (b2 - b0) * (b3 - b1);
  ws->tsc[r] = s;
  ws->tcls[r] = c;
  out[r * 4 + 0] = (float)b0;
  out[r * 4 + 1] = (float)b1;
  out[r * 4 + 2] = (float)b2;
  out[r * 4 + 3] = (float)b3;
  out[4 * TOPK_N + r] = (float)s;
  out[5 * TOPK_N + r] = (float)c;
}

// supT[i*64+w]: bit t set iff j=w*64+t suppresses i (same class, iou>0.6, j<i)
__global__ void k_iou(WS* __restrict__ ws) {
  __shared__ double jb[64][5];
  __shared__ int jc[64];
  int tid = threadIdx.x;
  int w = blockIdx.y;
  if (tid < 64) {
    int j = w * 64 + tid;
    jb[tid][0] = ws->tbox[j][0];
    jb[tid][1] = ws->tbox[j][1];
    jb[tid][2] = ws->tbox[j][2];
    jb[tid][3] = ws->tbox[j][3];
    jb[tid][4] = ws->tarea[j];
    jc[tid] = ws->tcls[j];
  }
  __syncthreads();
  int i = blockIdx.x * 256 + tid;
  double x1 = ws->tbox[i][0], y1 = ws->tbox[i][1];
  double x2 = ws->tbox[i][2], y2 = ws->tbox[i][3];
  double ai = ws->tarea[i];
  int ci = ws->tcls[i];
  u64 bits = 0;
  int jbase = w * 64;
  for (int t = 0; t < 64; ++t) {
    double xx1 = fmax(x1, jb[t][0]);
    double yy1 = fmax(y1, jb[t][1]);
    double xx2 = fmin(x2, jb[t][2]);
    double yy2 = fmin(y2, jb[t][3]);
    double iw = fmax(1e-28, xx2 - xx1);
    double ih = fmax(1e-28, yy2 - yy1);
    double inter = iw * ih;
    double denom = ai + jb[t][4] - inter + 1e-14;
    // iou > 0.6  <=>  inter > 0.6*denom   (denom > 0)
    bool sup = (jc[t] == ci) && (inter > NMS_T * denom) && ((jbase + t) < i);
    bits |= ((u64)sup) << t;
  }
  ws->supT[(size_t)i * 64 + w] = bits;
}

// single-wave greedy scan: lane l holds keep bits for j in [64l, 64l+64)
__global__ void __launch_bounds__(64) k_nms(const WS* __restrict__ ws, float* __restrict__ out) {
  int lane = threadIdx.x;
  u64 validw = 0, keepw = 0;
  for (int b = 0; b < 64; ++b)
    validw |= ((u64)(ws->tsc[lane * 64 + b] >= CONF_T)) << b;

  const u64* ST = ws->supT;
  u64 A[16], B[16];
#pragma unroll
  for (int r = 0; r < 16; ++r) A[r] = ST[(size_t)r * 64 + lane];

#define PROC(BUF, BASE)                                                     \
  _Pragma("unroll")                                                         \
  for (int r = 0; r < 16; ++r) {                                            \
    int i = (BASE) + r;                                                     \
    u64 hit = keepw & BUF[r];                                               \
    u64 bal = __ballot(hit != 0ull);                                        \
    int w_ = i >> 6, b_ = i & 63;                                           \
    if (lane == w_ && bal == 0ull && ((validw >> b_) & 1ull))               \
      keepw |= (1ull << b_);                                                \
  }

  for (int c = 0; c < 256; c += 2) {
    if (c + 1 < 256) {
#pragma unroll
      for (int r = 0; r < 16; ++r) B[r] = ST[(size_t)((c + 1) * 16 + r) * 64 + lane];
    }
    PROC(A, c * 16)
    if (c + 2 < 256) {
#pragma unroll
      for (int r = 0; r < 16; ++r) A[r] = ST[(size_t)((c + 2) * 16 + r) * 64 + lane];
    }
    PROC(B, (c + 1) * 16)
  }
#undef PROC

  for (int b = 0; b < 64; ++b)
    out[6 * TOPK_N + lane * 64 + b] = (float)((keepw >> b) & 1ull);
}

extern "C" void kernel_launch(void* const* d_in, const int* in_sizes, int n_in,
                              void* d_out, int out_size, void* d_ws, size_t ws_size,
                              hipStream_t stream) {
  const float* ps   = (const float*)d_in[0];
  const float* pm   = (const float*)d_in[1];
  const float* pl   = (const float*)d_in[2];
  const float* anch = (const float*)d_in[3];
  float* out = (float*)d_out;
  WS* ws = (WS*)d_ws;

  dim3 blk(256);
  k_decode<<<dim3((N_ANCH + 255) / 256), blk, 0, stream>>>(ps, pm, pl, anch, ws);
  k_count<<<dim3((N_ANCH + 255) / 256, 16), blk, 0, stream>>>(ws);
  k_scatter<<<dim3((N_ANCH + 255) / 256), blk, 0, stream>>>(ws, out);
  k_iou<<<dim3(TOPK_N / 256, 64), blk, 0, stream>>>(ws);
  k_nms<<<1, 64, 0, stream>>>(ws, out);
}

// Round 2
// 205.767 us; speedup vs baseline: 2.1582x; 2.1582x over previous
//
#include <hip/hip_runtime.h>
#include <cstdint>
#include <cstddef>

#define N_ANCH 25200
#define NB0 19200
#define NB1 24000
#define TOPK_N 4096
#define CONF_T 0.001
#define NMS_T 0.6
#define IMGS 640.0
#define CS 1575   // N_ANCH / 16 exactly

typedef unsigned long long u64;

struct WS {
  double sc[N_ANCH];          // masked score (sc or -1.0)
  double box[N_ANCH][4];      // clipped normalized boxes, fp64
  int    cls[N_ANCH];
  int    rank[N_ANCH];
  double tbox[TOPK_N][4];
  double tarea[TOPK_N];
  double tsc[TOPK_N];
  int    tcls[TOPK_N];
  u64    supT[TOPK_N * 64];   // supT[i*64+w] bit b: j=w*64+b suppresses i
  u64    hasSup[64];          // bit i of word (i>>6): row i has >=1 suppressor bit
};

__device__ __forceinline__ double dsigmoid(double x) { return 1.0 / (1.0 + exp(-x)); }

__global__ void k_decode(const float* __restrict__ ps, const float* __restrict__ pm,
                         const float* __restrict__ pl, const float* __restrict__ anch,
                         WS* __restrict__ ws) {
  int a = blockIdx.x * 256 + threadIdx.x;
  if (a >= N_ANCH) return;
  if (a < 64) ws->hasSup[a] = 0ull;   // zero bitmap for k_iou's atomicOr (ws is re-poisoned each call)
  const float* p; int W, base, lvl; double stride;
  if (a < NB0)      { p = ps; W = 80; base = 0;   lvl = 0; stride = 8.0; }
  else if (a < NB1) { p = pm; W = 40; base = NB0; lvl = 1; stride = 16.0; }
  else              { p = pl; W = 20; base = NB1; lvl = 2; stride = 32.0; }
  int e = a - base;
  int pos = e / 3;
  int k = e - 3 * pos;
  int HW = W * W;
  int x = pos % W, y = pos / W;

  // objectness
  double sobj = dsigmoid((double)p[(size_t)k * HW + pos]);

  // class softmax max + argmax (two-pass, fp64)
  const float* pc = p + (size_t)(3 + k * 80) * HW + pos;
  double m = -1e300; int am = 0;
  for (int c = 0; c < 80; ++c) {
    double v = (double)pc[(size_t)c * HW];
    if (v > m) { m = v; am = c; }
  }
  double ssum = 0.0;
  for (int c = 0; c < 80; ++c) {
    double v = (double)pc[(size_t)c * HW];
    ssum += exp(v - m);
  }
  double sc = sobj * (1.0 / ssum);

  // box decode
  const float* pr = p + (size_t)(243 + k * 4) * HW + pos;
  double tx = (double)pr[0];
  double ty = (double)pr[(size_t)HW];
  double tw = (double)pr[(size_t)2 * HW];
  double th = (double)pr[(size_t)3 * HW];
  double cx = (dsigmoid(tx) + (double)x) * stride;
  double cy = (dsigmoid(ty) + (double)y) * stride;
  double aw = (double)anch[lvl * 6 + k * 2 + 0];
  double ah = (double)anch[lvl * 6 + k * 2 + 1];
  double bw = exp(tw) * aw;
  double bh = exp(th) * ah;
  double x1 = fmin(fmax((cx - 0.5 * bw) / IMGS, 0.0), 1.0);
  double y1 = fmin(fmax((cy - 0.5 * bh) / IMGS, 0.0), 1.0);
  double x2 = fmin(fmax((cx + 0.5 * bw) / IMGS, 0.0), 1.0);
  double y2 = fmin(fmax((cy + 0.5 * bh) / IMGS, 0.0), 1.0);

  ws->box[a][0] = x1; ws->box[a][1] = y1;
  ws->box[a][2] = x2; ws->box[a][3] = y2;
  ws->cls[a] = am;
  ws->sc[a] = (sc >= CONF_T) ? sc : -1.0;
  ws->rank[a] = 0;
}

// rank[i] = #{ j : sc_j > sc_i  or (sc_j == sc_i and j < i) }
__global__ void k_count(WS* __restrict__ ws) {
  __shared__ double s[CS];
  int j0 = blockIdx.y * CS;
  for (int t = threadIdx.x; t < CS; t += 256) s[t] = ws->sc[j0 + t];
  __syncthreads();
  int i = blockIdx.x * 256 + threadIdx.x;
  if (i >= N_ANCH) return;
  double si = ws->sc[i];
  int cnt = 0;
  for (int t = 0; t < CS; ++t) {
    double sj = s[t];
    cnt += (int)((sj > si) | ((sj == si) & ((j0 + t) < i)));
  }
  atomicAdd(&ws->rank[i], cnt);
}

__global__ void k_scatter(WS* __restrict__ ws, float* __restrict__ out) {
  int i = blockIdx.x * 256 + threadIdx.x;
  if (i >= N_ANCH) return;
  int r = ws->rank[i];
  if (r >= TOPK_N) return;
  double b0 = ws->box[i][0], b1 = ws->box[i][1];
  double b2 = ws->box[i][2], b3 = ws->box[i][3];
  double s  = ws->sc[i];
  int    c  = ws->cls[i];
  ws->tbox[r][0] = b0; ws->tbox[r][1] = b1;
  ws->tbox[r][2] = b2; ws->tbox[r][3] = b3;
  ws->tarea[r] = (b2 - b0) * (b3 - b1);
  ws->tsc[r] = s;
  ws->tcls[r] = c;
  out[r * 4 + 0] = (float)b0;
  out[r * 4 + 1] = (float)b1;
  out[r * 4 + 2] = (float)b2;
  out[r * 4 + 3] = (float)b3;
  out[4 * TOPK_N + r] = (float)s;
  out[5 * TOPK_N + r] = (float)c;
}

// supT[i*64+w]: bit t set iff j=w*64+t suppresses i (same class, iou>0.6, j<i)
__global__ void k_iou(WS* __restrict__ ws) {
  __shared__ double jb[64][5];
  __shared__ int jc[64];
  int tid = threadIdx.x;
  int w = blockIdx.y;
  if (tid < 64) {
    int j = w * 64 + tid;
    jb[tid][0] = ws->tbox[j][0];
    jb[tid][1] = ws->tbox[j][1];
    jb[tid][2] = ws->tbox[j][2];
    jb[tid][3] = ws->tbox[j][3];
    jb[tid][4] = ws->tarea[j];
    jc[tid] = ws->tcls[j];
  }
  __syncthreads();
  int i = blockIdx.x * 256 + tid;
  double x1 = ws->tbox[i][0], y1 = ws->tbox[i][1];
  double x2 = ws->tbox[i][2], y2 = ws->tbox[i][3];
  double ai = ws->tarea[i];
  int ci = ws->tcls[i];
  u64 bits = 0;
  int jbase = w * 64;
  for (int t = 0; t < 64; ++t) {
    double xx1 = fmax(x1, jb[t][0]);
    double yy1 = fmax(y1, jb[t][1]);
    double xx2 = fmin(x2, jb[t][2]);
    double yy2 = fmin(y2, jb[t][3]);
    double iw = fmax(1e-28, xx2 - xx1);
    double ih = fmax(1e-28, yy2 - yy1);
    double inter = iw * ih;
    double denom = ai + jb[t][4] - inter + 1e-14;
    // iou > 0.6  <=>  inter > 0.6*denom   (denom > 0)
    bool sup = (jc[t] == ci) && (inter > NMS_T * denom) && ((jbase + t) < i);
    bits |= ((u64)sup) << t;
  }
  ws->supT[(size_t)i * 64 + w] = bits;
  if (bits) atomicOr(&ws->hasSup[i >> 6], 1ull << (i & 63));
}

// single-wave greedy scan over CONTESTED candidates only.
// lane l holds keep bits for j in [64l, 64l+64).
// Uncontested candidates (no suppressor bits in their row) are kept iff valid,
// set in bulk up front — correct because row i only references j < i, so
// "future" uncontested keep bits never corrupt an earlier ballot.
__global__ void __launch_bounds__(64) k_nms(const WS* __restrict__ ws, float* __restrict__ out) {
  __shared__ u64 hsArr[64];
  __shared__ int lst[TOPK_N];
  int lane = threadIdx.x;

  u64 validw = 0;
  for (int b = 0; b < 64; ++b)
    validw |= ((u64)(ws->tsc[lane * 64 + b] >= CONF_T)) << b;

  u64 hasw = ws->hasSup[lane];
  u64 keepw = validw & ~hasw;   // bulk-keep all uncontested valid candidates
  hsArr[lane] = hasw;
  __syncthreads();

  // build ascending list of contested indices (uniform computation; lane 0 writes)
  int K = 0;
  for (int l = 0; l < 64; ++l) {
    u64 w = hsArr[l];
    while (w) {
      int b = __builtin_ctzll(w);
      w &= w - 1;
      if (lane == 0) lst[K] = l * 64 + b;
      ++K;
    }
  }
  __syncthreads();

  const u64* ST = ws->supT;
  int IA[16], IB[16];
  u64 A[16], B[16];

#pragma unroll
  for (int r = 0; r < 16; ++r) IA[r] = (r < K) ? lst[r] : 0;
#pragma unroll
  for (int r = 0; r < 16; ++r) A[r] = (r < K) ? ST[(size_t)IA[r] * 64 + lane] : 0ull;

  for (int base = 0; base < K; base += 32) {
    // prefetch chunk base+16 (B)
#pragma unroll
    for (int r = 0; r < 16; ++r) IB[r] = (base + 16 + r < K) ? lst[base + 16 + r] : 0;
#pragma unroll
    for (int r = 0; r < 16; ++r) B[r] = (base + 16 + r < K) ? ST[(size_t)IB[r] * 64 + lane] : 0ull;
    // process chunk base (A)
#pragma unroll
    for (int r = 0; r < 16; ++r) {
      if (base + r < K) {
        int i = IA[r];
        u64 bal = __ballot((keepw & A[r]) != 0ull);
        if (lane == (i >> 6) && bal == 0ull && ((validw >> (i & 63)) & 1ull))
          keepw |= 1ull << (i & 63);
      }
    }
    // prefetch chunk base+32 (A)
#pragma unroll
    for (int r = 0; r < 16; ++r) IA[r] = (base + 32 + r < K) ? lst[base + 32 + r] : 0;
#pragma unroll
    for (int r = 0; r < 16; ++r) A[r] = (base + 32 + r < K) ? ST[(size_t)IA[r] * 64 + lane] : 0ull;
    // process chunk base+16 (B)
#pragma unroll
    for (int r = 0; r < 16; ++r) {
      if (base + 16 + r < K) {
        int i = IB[r];
        u64 bal = __ballot((keepw & B[r]) != 0ull);
        if (lane == (i >> 6) && bal == 0ull && ((validw >> (i & 63)) & 1ull))
          keepw |= 1ull << (i & 63);
      }
    }
  }

  for (int b = 0; b < 64; ++b)
    out[6 * TOPK_N + lane * 64 + b] = (float)((keepw >> b) & 1ull);
}

extern "C" void kernel_launch(void* const* d_in, const int* in_sizes, int n_in,
                              void* d_out, int out_size, void* d_ws, size_t ws_size,
                              hipStream_t stream) {
  const float* ps   = (const float*)d_in[0];
  const float* pm   = (const float*)d_in[1];
  const float* pl   = (const float*)d_in[2];
  const float* anch = (const float*)d_in[3];
  float* out = (float*)d_out;
  WS* ws = (WS*)d_ws;

  dim3 blk(256);
  k_decode<<<dim3((N_ANCH + 255) / 256), blk, 0, stream>>>(ps, pm, pl, anch, ws);
  k_count<<<dim3((N_ANCH + 255) / 256, 16), blk, 0, stream>>>(ws);
  k_scatter<<<dim3((N_ANCH + 255) / 256), blk, 0, stream>>>(ws, out);
  k_iou<<<dim3(TOPK_N / 256, 64), blk, 0, stream>>>(ws);
  k_nms<<<1, 64, 0, stream>>>(ws, out);
}

// Round 3
// 144.287 us; speedup vs baseline: 3.0778x; 1.4261x over previous
//
#include <hip/hip_runtime.h>
#include <cstdint>
#include <cstddef>

#define N_ANCH 25200
#define NB0 19200
#define NB1 24000
#define TOPK_N 4096
#define CONF_T 0.001
#define NMS_T 0.6
#define IMGS 640.0
#define NBINS 16384      // fp32 bits >> 16 (exponent + 7 mantissa bits), scores in (0,1)
#define JS 16            // j-split for k_rank

typedef unsigned long long u64;

struct WS {
  double sc[N_ANCH];          // masked score (sc or -1.0)
  double box[N_ANCH][4];      // clipped normalized boxes, fp64
  int    cls[N_ANCH];
  int    rank[N_ANCH];        // rank within subset (indexed by subset position)
  int    subset[N_ANCH];      // anchor ids with bin >= t_bin
  int    hist[NBINS];
  int    m_count;
  int    t_bin;
  double tbox[TOPK_N][4];
  double tarea[TOPK_N];
  double tsc[TOPK_N];
  int    tcls[TOPK_N];
  u64    supT[TOPK_N * 64];   // supT[i*64+w] bit b: j=w*64+b suppresses i
  u64    hasSup[64];          // bit i of word (i>>6): row i has >=1 suppressor bit
};

__device__ __forceinline__ double dsigmoid(double x) { return 1.0 / (1.0 + exp(-x)); }

__device__ __forceinline__ int score_bin(double sc) {
  if (sc < 0.0) return 0;                    // masked
  return (int)(__float_as_uint((float)sc) >> 16);  // monotone for positive floats
}

// zero hist + hasSup + counters (ws is re-poisoned 0xAA before every call)
__global__ void k_zero(WS* __restrict__ ws) {
  int t = blockIdx.x * 256 + threadIdx.x;
  ws->hist[t] = 0;                 // grid is exactly NBINS threads
  if (t < 64) ws->hasSup[t] = 0ull;
  if (t == 64) ws->m_count = 0;
  if (t == 65) ws->t_bin = 0;
}

__global__ void k_decode(const float* __restrict__ ps, const float* __restrict__ pm,
                         const float* __restrict__ pl, const float* __restrict__ anch,
                         WS* __restrict__ ws) {
  int a = blockIdx.x * 256 + threadIdx.x;
  if (a >= N_ANCH) return;
  const float* p; int W, base, lvl; double stride;
  if (a < NB0)      { p = ps; W = 80; base = 0;   lvl = 0; stride = 8.0; }
  else if (a < NB1) { p = pm; W = 40; base = NB0; lvl = 1; stride = 16.0; }
  else              { p = pl; W = 20; base = NB1; lvl = 2; stride = 32.0; }
  int e = a - base;
  int pos = e / 3;
  int k = e - 3 * pos;
  int HW = W * W;
  int x = pos % W, y = pos / W;

  // objectness
  double sobj = dsigmoid((double)p[(size_t)k * HW + pos]);

  // class max/argmax + softmax denom, single pass (no max-shift; |v| small, fp64 safe)
  const float* pc = p + (size_t)(3 + k * 80) * HW + pos;
  double m = -1e300, ssum = 0.0; int am = 0;
  for (int c = 0; c < 80; ++c) {
    double v = (double)pc[(size_t)c * HW];
    ssum += exp(v);
    if (v > m) { m = v; am = c; }
  }
  double sc = sobj * (exp(m) / ssum);

  // box decode
  const float* pr = p + (size_t)(243 + k * 4) * HW + pos;
  double tx = (double)pr[0];
  double ty = (double)pr[(size_t)HW];
  double tw = (double)pr[(size_t)2 * HW];
  double th = (double)pr[(size_t)3 * HW];
  double cx = (dsigmoid(tx) + (double)x) * stride;
  double cy = (dsigmoid(ty) + (double)y) * stride;
  double aw = (double)anch[lvl * 6 + k * 2 + 0];
  double ah = (double)anch[lvl * 6 + k * 2 + 1];
  double bw = exp(tw) * aw;
  double bh = exp(th) * ah;
  double x1 = fmin(fmax((cx - 0.5 * bw) / IMGS, 0.0), 1.0);
  double y1 = fmin(fmax((cy - 0.5 * bh) / IMGS, 0.0), 1.0);
  double x2 = fmin(fmax((cx + 0.5 * bw) / IMGS, 0.0), 1.0);
  double y2 = fmin(fmax((cy + 0.5 * bh) / IMGS, 0.0), 1.0);

  ws->box[a][0] = x1; ws->box[a][1] = y1;
  ws->box[a][2] = x2; ws->box[a][3] = y2;
  ws->cls[a] = am;
  double scm = (sc >= CONF_T) ? sc : -1.0;
  ws->sc[a] = scm;
  atomicAdd(&ws->hist[score_bin(scm)], 1);
}

// find t_bin = max b such that #{elements with bin >= b} >= TOPK_N.
// S(0) = N_ANCH >= TOPK_N always, so a crossing always exists and m_count >= TOPK_N.
__global__ void k_select(WS* __restrict__ ws) {
  __shared__ int part[256];
  int t = threadIdx.x;
  const int CH = NBINS / 256;   // 64 bins per thread, reversed (from top bin down)
  int sum = 0;
  for (int r = 0; r < CH; ++r) sum += ws->hist[NBINS - 1 - (t * CH + r)];
  part[t] = sum;
  __syncthreads();
  // inclusive Hillis-Steele scan over part[]
  for (int off = 1; off < 256; off <<= 1) {
    int v = (t >= off) ? part[t - off] : 0;
    __syncthreads();
    part[t] += v;
    __syncthreads();
  }
  int exc = part[t] - sum;  // exclusive prefix (count in bins above this thread's chunk)
  int cum = exc;
  for (int r = 0; r < CH; ++r) {
    int b = NBINS - 1 - (t * CH + r);
    int h = ws->hist[b];
    int prev = cum;
    cum += h;
    if (prev < TOPK_N && cum >= TOPK_N) ws->t_bin = b;  // unique crossing thread
  }
}

__global__ void k_compact(WS* __restrict__ ws) {
  int i = blockIdx.x * 256 + threadIdx.x;
  if (i >= N_ANCH) return;
  int tb = ws->t_bin;
  if (score_bin(ws->sc[i]) >= tb) {
    int idx = atomicAdd(&ws->m_count, 1);
    ws->subset[idx] = i;
    ws->rank[idx] = 0;
  }
}

// exact rank within subset: rank[i] = #{ j in subset : sc_j > sc_i or (sc_j==sc_i && aj<ai) }
__global__ void k_rank(WS* __restrict__ ws) {
  const int CHUNK = 1024;
  __shared__ double sj[CHUNK];
  __shared__ int    aj[CHUNK];
  int m = ws->m_count;
  if ((int)blockIdx.x * 256 >= m) return;   // block-uniform exit
  int i = blockIdx.x * 256 + threadIdx.x;
  bool active = (i < m);
  int ai = active ? ws->subset[i] : 0;
  double si = active ? ws->sc[ai] : -2.0;

  int jlen = (m + JS - 1) / JS;
  int j0 = blockIdx.y * jlen;
  int jend = min(j0 + jlen, m);
  int cnt = 0;
  for (int jc = j0; jc < jend; jc += CHUNK) {
    int n = min(CHUNK, jend - jc);
    __syncthreads();
    for (int t = threadIdx.x; t < n; t += 256) {
      int a = ws->subset[jc + t];
      aj[t] = a;
      sj[t] = ws->sc[a];
    }
    __syncthreads();
    if (active) {
      for (int t = 0; t < n; ++t) {
        double s = sj[t];
        cnt += (int)((s > si) | ((s == si) & (aj[t] < ai)));
      }
    }
  }
  if (active && cnt) atomicAdd(&ws->rank[i], cnt);
}

__global__ void k_scatter(WS* __restrict__ ws, float* __restrict__ out) {
  int m = ws->m_count;
  int i = blockIdx.x * 256 + threadIdx.x;
  if (i >= m) return;
  int r = ws->rank[i];
  if (r >= TOPK_N) return;
  int a = ws->subset[i];
  double b0 = ws->box[a][0], b1 = ws->box[a][1];
  double b2 = ws->box[a][2], b3 = ws->box[a][3];
  double s  = ws->sc[a];
  int    c  = ws->cls[a];
  ws->tbox[r][0] = b0; ws->tbox[r][1] = b1;
  ws->tbox[r][2] = b2; ws->tbox[r][3] = b3;
  ws->tarea[r] = (b2 - b0) * (b3 - b1);
  ws->tsc[r] = s;
  ws->tcls[r] = c;
  out[r * 4 + 0] = (float)b0;
  out[r * 4 + 1] = (float)b1;
  out[r * 4 + 2] = (float)b2;
  out[r * 4 + 3] = (float)b3;
  out[4 * TOPK_N + r] = (float)s;
  out[5 * TOPK_N + r] = (float)c;
}

// supT[i*64+w]: bit t set iff j=w*64+t suppresses i (same class, iou>0.6, j<i)
__global__ void k_iou(WS* __restrict__ ws) {
  __shared__ double jb[64][5];
  __shared__ int jc[64];
  int tid = threadIdx.x;
  int w = blockIdx.y;
  if (tid < 64) {
    int j = w * 64 + tid;
    jb[tid][0] = ws->tbox[j][0];
    jb[tid][1] = ws->tbox[j][1];
    jb[tid][2] = ws->tbox[j][2];
    jb[tid][3] = ws->tbox[j][3];
    jb[tid][4] = ws->tarea[j];
    jc[tid] = ws->tcls[j];
  }
  __syncthreads();
  int i = blockIdx.x * 256 + tid;
  double x1 = ws->tbox[i][0], y1 = ws->tbox[i][1];
  double x2 = ws->tbox[i][2], y2 = ws->tbox[i][3];
  double ai = ws->tarea[i];
  int ci = ws->tcls[i];
  u64 bits = 0;
  int jbase = w * 64;
  for (int t = 0; t < 64; ++t) {
    double xx1 = fmax(x1, jb[t][0]);
    double yy1 = fmax(y1, jb[t][1]);
    double xx2 = fmin(x2, jb[t][2]);
    double yy2 = fmin(y2, jb[t][3]);
    double iw = fmax(1e-28, xx2 - xx1);
    double ih = fmax(1e-28, yy2 - yy1);
    double inter = iw * ih;
    double denom = ai + jb[t][4] - inter + 1e-14;
    bool sup = (jc[t] == ci) && (inter > NMS_T * denom) && ((jbase + t) < i);
    bits |= ((u64)sup) << t;
  }
  ws->supT[(size_t)i * 64 + w] = bits;
  if (bits) atomicOr(&ws->hasSup[i >> 6], 1ull << (i & 63));
}

// single-wave greedy scan over CONTESTED candidates only (see R2 notes).
__global__ void __launch_bounds__(64) k_nms(const WS* __restrict__ ws, float* __restrict__ out) {
  __shared__ u64 hsArr[64];
  __shared__ int lst[TOPK_N];
  int lane = threadIdx.x;

  u64 validw = 0;
  for (int b = 0; b < 64; ++b)
    validw |= ((u64)(ws->tsc[lane * 64 + b] >= CONF_T)) << b;

  u64 hasw = ws->hasSup[lane];
  u64 keepw = validw & ~hasw;   // bulk-keep uncontested valid candidates
  hsArr[lane] = hasw;
  __syncthreads();

  int K = 0;
  for (int l = 0; l < 64; ++l) {
    u64 w = hsArr[l];
    while (w) {
      int b = __builtin_ctzll(w);
      w &= w - 1;
      if (lane == 0) lst[K] = l * 64 + b;
      ++K;
    }
  }
  __syncthreads();

  const u64* ST = ws->supT;
  int IA[16], IB[16];
  u64 A[16], B[16];

#pragma unroll
  for (int r = 0; r < 16; ++r) IA[r] = (r < K) ? lst[r] : 0;
#pragma unroll
  for (int r = 0; r < 16; ++r) A[r] = (r < K) ? ST[(size_t)IA[r] * 64 + lane] : 0ull;

  for (int base = 0; base < K; base += 32) {
#pragma unroll
    for (int r = 0; r < 16; ++r) IB[r] = (base + 16 + r < K) ? lst[base + 16 + r] : 0;
#pragma unroll
    for (int r = 0; r < 16; ++r) B[r] = (base + 16 + r < K) ? ST[(size_t)IB[r] * 64 + lane] : 0ull;
#pragma unroll
    for (int r = 0; r < 16; ++r) {
      if (base + r < K) {
        int i = IA[r];
        u64 bal = __ballot((keepw & A[r]) != 0ull);
        if (lane == (i >> 6) && bal == 0ull && ((validw >> (i & 63)) & 1ull))
          keepw |= 1ull << (i & 63);
      }
    }
#pragma unroll
    for (int r = 0; r < 16; ++r) IA[r] = (base + 32 + r < K) ? lst[base + 32 + r] : 0;
#pragma unroll
    for (int r = 0; r < 16; ++r) A[r] = (base + 32 + r < K) ? ST[(size_t)IA[r] * 64 + lane] : 0ull;
#pragma unroll
    for (int r = 0; r < 16; ++r) {
      if (base + 16 + r < K) {
        int i = IB[r];
        u64 bal = __ballot((keepw & B[r]) != 0ull);
        if (lane == (i >> 6) && bal == 0ull && ((validw >> (i & 63)) & 1ull))
          keepw |= 1ull << (i & 63);
      }
    }
  }

  for (int b = 0; b < 64; ++b)
    out[6 * TOPK_N + lane * 64 + b] = (float)((keepw >> b) & 1ull);
}

extern "C" void kernel_launch(void* const* d_in, const int* in_sizes, int n_in,
                              void* d_out, int out_size, void* d_ws, size_t ws_size,
                              hipStream_t stream) {
  const float* ps   = (const float*)d_in[0];
  const float* pm   = (const float*)d_in[1];
  const float* pl   = (const float*)d_in[2];
  const float* anch = (const float*)d_in[3];
  float* out = (float*)d_out;
  WS* ws = (WS*)d_ws;

  dim3 blk(256);
  k_zero   <<<dim3(NBINS / 256), blk, 0, stream>>>(ws);
  k_decode <<<dim3((N_ANCH + 255) / 256), blk, 0, stream>>>(ps, pm, pl, anch, ws);
  k_select <<<dim3(1), blk, 0, stream>>>(ws);
  k_compact<<<dim3((N_ANCH + 255) / 256), blk, 0, stream>>>(ws);
  k_rank   <<<dim3((N_ANCH + 255) / 256, JS), blk, 0, stream>>>(ws);
  k_scatter<<<dim3((N_ANCH + 255) / 256), blk, 0, stream>>>(ws, out);
  k_iou    <<<dim3(TOPK_N / 256, 64), blk, 0, stream>>>(ws);
  k_nms    <<<dim3(1), dim3(64), 0, stream>>>(ws, out);
}

// Round 4
// 123.559 us; speedup vs baseline: 3.5942x; 1.1678x over previous
//
#include <hip/hip_runtime.h>
#include <cstdint>
#include <cstddef>

#define N_ANCH 25200
#define NB0 19200
#define NB1 24000
#define TOPK_N 4096
#define CONF_T 0.001
#define NMS_T 0.6
#define IMGS 640.0
#define NBINS 8192       // fp32 bits >> 17 (exponent + 6 mantissa bits), scores in (0,2)
#define JS 16            // j-split for k_rank

typedef unsigned long long u64;

struct WS {
  alignas(64) double sc[N_ANCH];       // masked score (sc or -1.0)
  alignas(64) double box[N_ANCH][4];   // clipped normalized boxes, fp64
  alignas(64) int    cls[N_ANCH];
  alignas(64) int    binv[N_ANCH];     // score bin per anchor
  alignas(64) int    rank[N_ANCH];     // rank within subset (by subset position)
  alignas(64) int    subset[N_ANCH];   // anchor ids with bin >= t_bin
  alignas(64) double ssc[N_ANCH];      // packed scores of subset
  int    m_count;
  int    t_bin;
  alignas(64) double tbox[TOPK_N][4];
  alignas(64) double tarea[TOPK_N];
  alignas(64) double tsc[TOPK_N];
  alignas(64) int    tcls[TOPK_N];
  alignas(64) u64    supT[TOPK_N * 64]; // supT[i*64+w] bit b: j=w*64+b suppresses i
  alignas(64) u64    hasSup[64];        // bit i of word (i>>6): row i has >=1 suppressor
};

__device__ __forceinline__ double dsigmoid(double x) { return 1.0 / (1.0 + exp(-x)); }

__device__ __forceinline__ int score_bin(double sc) {
  if (sc < 0.0) return 0;                          // masked
  return (int)(__float_as_uint((float)sc) >> 17);  // monotone for positive floats, < 8192
}

// 4 lanes per anchor: lane r of a team handles classes c ≡ r (mod 4).
__global__ void k_decode(const float* __restrict__ ps, const float* __restrict__ pm,
                         const float* __restrict__ pl, const float* __restrict__ anch,
                         WS* __restrict__ ws) {
  int tid = blockIdx.x * 256 + threadIdx.x;
  int a = tid >> 2;
  int r = tid & 3;
  if (a >= N_ANCH) return;   // team-uniform (4-aligned)
  const float* p; int W, base, lvl; double stride;
  if (a < NB0)      { p = ps; W = 80; base = 0;   lvl = 0; stride = 8.0; }
  else if (a < NB1) { p = pm; W = 40; base = NB0; lvl = 1; stride = 16.0; }
  else              { p = pl; W = 20; base = NB1; lvl = 2; stride = 32.0; }
  int e = a - base;
  int pos = e / 3;
  int k = e - 3 * pos;
  int HW = W * W;

  // class max/argmax + softmax denom, 20 classes per lane
  const float* pc = p + (size_t)(3 + k * 80) * HW + pos;
  double m = -1e300, ssum = 0.0; int am = 0;
  for (int t = 0; t < 20; ++t) {
    int c = r + 4 * t;
    double v = (double)pc[(size_t)c * HW];
    ssum += exp(v);
    if (v > m) { m = v; am = c; }  // strict > keeps first occurrence per lane
  }
  // team reduction (lanes r^1, r^2 are in the same 4-lane group within the wave)
  for (int off = 1; off <= 2; off <<= 1) {
    double om = __shfl_xor(m, off);
    int oam   = __shfl_xor(am, off);
    double os = __shfl_xor(ssum, off);
    ssum += os;
    if (om > m || (om == m && oam < am)) { m = om; am = oam; }  // first-max tie-break
  }

  if (r == 0) {
    double sobj = dsigmoid((double)p[(size_t)k * HW + pos]);
    double sc = sobj * (exp(m) / ssum);

    int x = pos % W, y = pos / W;
    const float* pr = p + (size_t)(243 + k * 4) * HW + pos;
    double tx = (double)pr[0];
    double ty = (double)pr[(size_t)HW];
    double tw = (double)pr[(size_t)2 * HW];
    double th = (double)pr[(size_t)3 * HW];
    double cx = (dsigmoid(tx) + (double)x) * stride;
    double cy = (dsigmoid(ty) + (double)y) * stride;
    double aw = (double)anch[lvl * 6 + k * 2 + 0];
    double ah = (double)anch[lvl * 6 + k * 2 + 1];
    double bw = exp(tw) * aw;
    double bh = exp(th) * ah;
    double x1 = fmin(fmax((cx - 0.5 * bw) / IMGS, 0.0), 1.0);
    double y1 = fmin(fmax((cy - 0.5 * bh) / IMGS, 0.0), 1.0);
    double x2 = fmin(fmax((cx + 0.5 * bw) / IMGS, 0.0), 1.0);
    double y2 = fmin(fmax((cy + 0.5 * bh) / IMGS, 0.0), 1.0);

    ws->box[a][0] = x1; ws->box[a][1] = y1;
    ws->box[a][2] = x2; ws->box[a][3] = y2;
    ws->cls[a] = am;
    double scm = (sc >= CONF_T) ? sc : -1.0;
    ws->sc[a] = scm;
    ws->binv[a] = score_bin(scm);
  }
}

// single block: LDS hist over binv, then t_bin = max b with #{bin >= b} >= TOPK_N.
// S(0) = N_ANCH >= TOPK_N always, so the crossing exists.
__global__ void __launch_bounds__(1024) k_select(WS* __restrict__ ws) {
  __shared__ int hist[NBINS];   // 32 KB
  __shared__ int part[1024];
  int t = threadIdx.x;
  for (int i = t; i < NBINS; i += 1024) hist[i] = 0;
  __syncthreads();
  for (int i = t; i < N_ANCH; i += 1024) atomicAdd(&hist[ws->binv[i]], 1);
  __syncthreads();
  const int CH = NBINS / 1024;  // 8 reversed bins per thread
  int sum = 0;
  for (int rr = 0; rr < CH; ++rr) sum += hist[NBINS - 1 - (t * CH + rr)];
  part[t] = sum;
  __syncthreads();
  for (int off = 1; off < 1024; off <<= 1) {
    int v = (t >= off) ? part[t - off] : 0;
    __syncthreads();
    part[t] += v;
    __syncthreads();
  }
  int cum = part[t] - sum;  // count in bins above this thread's chunk
  for (int rr = 0; rr < CH; ++rr) {
    int b = NBINS - 1 - (t * CH + rr);
    int h = hist[b];
    int prev = cum;
    cum += h;
    if (prev < TOPK_N && cum >= TOPK_N) ws->t_bin = b;  // unique crossing thread
  }
  if (t == 0) ws->m_count = 0;
}

__global__ void k_compact(WS* __restrict__ ws) {
  int i = blockIdx.x * 256 + threadIdx.x;
  if (i < 64) ws->hasSup[i] = 0ull;   // zero for k_iou's atomicOr
  if (i >= N_ANCH) return;
  int tb = ws->t_bin;
  if (ws->binv[i] >= tb) {
    int idx = atomicAdd(&ws->m_count, 1);
    ws->subset[idx] = i;
    ws->ssc[idx] = ws->sc[i];
    ws->rank[idx] = 0;
  }
}

// exact rank within subset: rank[i] = #{ j : sc_j > sc_i or (sc_j==sc_i && aj<ai) }
__global__ void k_rank(WS* __restrict__ ws) {
  const int CHUNK = 1024;
  __shared__ double sj[CHUNK];
  __shared__ int    aj[CHUNK];
  int m = ws->m_count;
  if ((int)blockIdx.x * 256 >= m) return;   // block-uniform exit
  int i = blockIdx.x * 256 + threadIdx.x;
  bool active = (i < m);
  int ai = active ? ws->subset[i] : 0;
  double si = active ? ws->ssc[i] : -2.0;

  int jlen = (m + JS - 1) / JS;
  int j0 = blockIdx.y * jlen;
  int jend = min(j0 + jlen, m);
  int cnt = 0;
  for (int jc = j0; jc < jend; jc += CHUNK) {
    int n = min(CHUNK, jend - jc);
    __syncthreads();
    for (int t = threadIdx.x; t < n; t += 256) {
      aj[t] = ws->subset[jc + t];
      sj[t] = ws->ssc[jc + t];
    }
    __syncthreads();
    if (active) {
      for (int t = 0; t < n; ++t) {
        double s = sj[t];
        cnt += (int)((s > si) | ((s == si) & (aj[t] < ai)));
      }
    }
  }
  if (active && cnt) atomicAdd(&ws->rank[i], cnt);
}

__global__ void k_scatter(WS* __restrict__ ws, float* __restrict__ out) {
  int m = ws->m_count;
  int i = blockIdx.x * 256 + threadIdx.x;
  if (i >= m) return;
  int r = ws->rank[i];
  if (r >= TOPK_N) return;
  int a = ws->subset[i];
  double b0 = ws->box[a][0], b1 = ws->box[a][1];
  double b2 = ws->box[a][2], b3 = ws->box[a][3];
  double s  = ws->ssc[i];
  int    c  = ws->cls[a];
  ws->tbox[r][0] = b0; ws->tbox[r][1] = b1;
  ws->tbox[r][2] = b2; ws->tbox[r][3] = b3;
  ws->tarea[r] = (b2 - b0) * (b3 - b1);
  ws->tsc[r] = s;
  ws->tcls[r] = c;
  out[r * 4 + 0] = (float)b0;
  out[r * 4 + 1] = (float)b1;
  out[r * 4 + 2] = (float)b2;
  out[r * 4 + 3] = (float)b3;
  out[4 * TOPK_N + r] = (float)s;
  out[5 * TOPK_N + r] = (float)c;
}

// supT[i*64+w]: bit t set iff j=w*64+t suppresses i (same class, iou>0.6, j<i).
// Upper-triangle blocks (all j >= i) write zeros without computing.
__global__ void k_iou(WS* __restrict__ ws) {
  int tid = threadIdx.x;
  int w = blockIdx.y;
  int i0 = blockIdx.x * 256;
  int jbase = w * 64;
  if (jbase >= i0 + 256) {                       // block-uniform: whole block is j > i
    ws->supT[(size_t)(i0 + tid) * 64 + w] = 0ull;
    return;
  }
  __shared__ double jb[64][5];
  __shared__ int jc[64];
  if (tid < 64) {
    int j = jbase + tid;
    jb[tid][0] = ws->tbox[j][0];
    jb[tid][1] = ws->tbox[j][1];
    jb[tid][2] = ws->tbox[j][2];
    jb[tid][3] = ws->tbox[j][3];
    jb[tid][4] = ws->tarea[j];
    jc[tid] = ws->tcls[j];
  }
  __syncthreads();
  int i = i0 + tid;
  double x1 = ws->tbox[i][0], y1 = ws->tbox[i][1];
  double x2 = ws->tbox[i][2], y2 = ws->tbox[i][3];
  double ai = ws->tarea[i];
  int ci = ws->tcls[i];
  u64 bits = 0;
  for (int t = 0; t < 64; ++t) {
    double xx1 = fmax(x1, jb[t][0]);
    double yy1 = fmax(y1, jb[t][1]);
    double xx2 = fmin(x2, jb[t][2]);
    double yy2 = fmin(y2, jb[t][3]);
    double iw = fmax(1e-28, xx2 - xx1);
    double ih = fmax(1e-28, yy2 - yy1);
    double inter = iw * ih;
    double denom = ai + jb[t][4] - inter + 1e-14;
    bool sup = (jc[t] == ci) && (inter > NMS_T * denom) && ((jbase + t) < i);
    bits |= ((u64)sup) << t;
  }
  ws->supT[(size_t)i * 64 + w] = bits;
  if (bits) atomicOr(&ws->hasSup[i >> 6], 1ull << (i & 63));
}

// single-wave greedy scan over CONTESTED candidates only (see R2 notes).
__global__ void __launch_bounds__(64) k_nms(const WS* __restrict__ ws, float* __restrict__ out) {
  __shared__ u64 hsArr[64];
  __shared__ int lst[TOPK_N];
  int lane = threadIdx.x;

  u64 validw = 0;
  const double4* tp = (const double4*)(ws->tsc + lane * 64);
  for (int q = 0; q < 16; ++q) {
    double4 v = tp[q];
    validw |= ((u64)(v.x >= CONF_T)) << (q * 4 + 0);
    validw |= ((u64)(v.y >= CONF_T)) << (q * 4 + 1);
    validw |= ((u64)(v.z >= CONF_T)) << (q * 4 + 2);
    validw |= ((u64)(v.w >= CONF_T)) << (q * 4 + 3);
  }

  u64 hasw = ws->hasSup[lane];
  u64 keepw = validw & ~hasw;   // bulk-keep uncontested valid candidates
  hsArr[lane] = hasw;
  __syncthreads();

  int K = 0;
  for (int l = 0; l < 64; ++l) {
    u64 w = hsArr[l];
    while (w) {
      int b = __builtin_ctzll(w);
      w &= w - 1;
      if (lane == 0) lst[K] = l * 64 + b;
      ++K;
    }
  }
  __syncthreads();

  const u64* ST = ws->supT;
  int IA[16], IB[16];
  u64 A[16], B[16];

#pragma unroll
  for (int r = 0; r < 16; ++r) IA[r] = (r < K) ? lst[r] : 0;
#pragma unroll
  for (int r = 0; r < 16; ++r) A[r] = (r < K) ? ST[(size_t)IA[r] * 64 + lane] : 0ull;

  for (int base = 0; base < K; base += 32) {
#pragma unroll
    for (int r = 0; r < 16; ++r) IB[r] = (base + 16 + r < K) ? lst[base + 16 + r] : 0;
#pragma unroll
    for (int r = 0; r < 16; ++r) B[r] = (base + 16 + r < K) ? ST[(size_t)IB[r] * 64 + lane] : 0ull;
#pragma unroll
    for (int r = 0; r < 16; ++r) {
      if (base + r < K) {
        int i = IA[r];
        u64 bal = __ballot((keepw & A[r]) != 0ull);
        if (lane == (i >> 6) && bal == 0ull && ((validw >> (i & 63)) & 1ull))
          keepw |= 1ull << (i & 63);
      }
    }
#pragma unroll
    for (int r = 0; r < 16; ++r) IA[r] = (base + 32 + r < K) ? lst[base + 32 + r] : 0;
#pragma unroll
    for (int r = 0; r < 16; ++r) A[r] = (base + 32 + r < K) ? ST[(size_t)IA[r] * 64 + lane] : 0ull;
#pragma unroll
    for (int r = 0; r < 16; ++r) {
      if (base + 16 + r < K) {
        int i = IB[r];
        u64 bal = __ballot((keepw & B[r]) != 0ull);
        if (lane == (i >> 6) && bal == 0ull && ((validw >> (i & 63)) & 1ull))
          keepw |= 1ull << (i & 63);
      }
    }
  }

  for (int b = 0; b < 64; ++b)
    out[6 * TOPK_N + lane * 64 + b] = (float)((keepw >> b) & 1ull);
}

extern "C" void kernel_launch(void* const* d_in, const int* in_sizes, int n_in,
                              void* d_out, int out_size, void* d_ws, size_t ws_size,
                              hipStream_t stream) {
  const float* ps   = (const float*)d_in[0];
  const float* pm   = (const float*)d_in[1];
  const float* pl   = (const float*)d_in[2];
  const float* anch = (const float*)d_in[3];
  float* out = (float*)d_out;
  WS* ws = (WS*)d_ws;

  dim3 blk(256);
  k_decode <<<dim3((N_ANCH * 4 + 255) / 256), blk, 0, stream>>>(ps, pm, pl, anch, ws);
  k_select <<<dim3(1), dim3(1024), 0, stream>>>(ws);
  k_compact<<<dim3((N_ANCH + 255) / 256), blk, 0, stream>>>(ws);
  k_rank   <<<dim3((N_ANCH + 255) / 256, JS), blk, 0, stream>>>(ws);
  k_scatter<<<dim3((N_ANCH + 255) / 256), blk, 0, stream>>>(ws, out);
  k_iou    <<<dim3(TOPK_N / 256, 64), blk, 0, stream>>>(ws);
  k_nms    <<<dim3(1), dim3(64), 0, stream>>>(ws, out);
}